// Round 10
// baseline (422.550 us; speedup 1.0000x reference)
//
#include <hip/hip_runtime.h>
#include <hip/hip_bf16.h>

typedef short s16x4 __attribute__((ext_vector_type(4)));
typedef short s16x8 __attribute__((ext_vector_type(8)));
typedef __bf16 bf16x8 __attribute__((ext_vector_type(8)));
typedef float f32x4 __attribute__((ext_vector_type(4)));

#define DEVI static __device__ __forceinline__
#define QSCALE 0.18033688011112042f   // 0.125 * log2(e)

DEVI unsigned short f2bf(float x) {
  union { float f; unsigned u; } a; a.f = x;
  unsigned r = a.u + 0x7fffu + ((a.u >> 16) & 1u);
  return (unsigned short)(r >> 16);
}
DEVI bf16x8 asbf(s16x8 v) {
  union { s16x8 s; bf16x8 b; } u; u.s = v; return u.b;
}
DEVI unsigned cvtpk(float lo, float hi) {
  unsigned r;
  asm("v_cvt_pk_bf16_f32 %0, %1, %2" : "=v"(r) : "v"(lo), "v"(hi));
  return r;
}
DEVI void gload16(const void* g, void* l) {
  __builtin_amdgcn_global_load_lds(
      (const __attribute__((address_space(1))) void*)g,
      (__attribute__((address_space(3))) void*)l, 16, 0, 0);
}

// ---------------------------------------------------------------------------
// prep: one launch doing (a) fp32->bf16 convert of x|ref, pre-swizzled
// (blocks 0..5119) and (b) 6x weight transpose+convert, pre-swizzled
// (blocks 5120..6655). Wq (z==0) is pre-scaled by QSCALE.
// ---------------------------------------------------------------------------
struct PrepArgs {
  const float* x; const float* ref; unsigned short* xg;
  const float* w[6]; unsigned short* o[6];
};

__global__ __launch_bounds__(256)
void prep(PrepArgs a) {
  __shared__ short tile[64][65];
  const int bid = blockIdx.x, t = threadIdx.x;
  if (bid < 5120) {
    int f = bid * 256 + t;
    int row = f >> 7, c8 = f & 127;
    const float* src = (row < 8192 ? a.x + (size_t)row * 1024
                                   : a.ref + (size_t)(row - 8192) * 1024) + c8 * 8;
    float4 v0 = *(const float4*)src;
    float4 v1 = *(const float4*)(src + 4);
    s16x8 o;
    o[0] = (short)f2bf(v0.x); o[1] = (short)f2bf(v0.y);
    o[2] = (short)f2bf(v0.z); o[3] = (short)f2bf(v0.w);
    o[4] = (short)f2bf(v1.x); o[5] = (short)f2bf(v1.y);
    o[6] = (short)f2bf(v1.z); o[7] = (short)f2bf(v1.w);
    int cs = (c8 & ~7) | ((c8 ^ row) & 7);
    *(s16x8*)(a.xg + (size_t)row * 1024 + cs * 8) = o;
  } else {
    int q = bid - 5120;
    int z = q >> 8, b2 = q & 255;
    const float* __restrict__ W = a.w[z];
    unsigned short* __restrict__ WT = a.o[z];
    const float sc = (z == 0) ? QSCALE : 1.0f;
    const int n0 = (b2 & 15) * 64;
    const int k0 = (b2 >> 4) * 64;
#pragma unroll
    for (int i = 0; i < 4; i++) {
      int f = t + i * 256;
      int r = f >> 4, c = (f & 15) * 4;
      float4 v = *(const float4*)(W + (size_t)(k0 + r) * 1024 + n0 + c);
      tile[r][c + 0] = (short)f2bf(v.x * sc);
      tile[r][c + 1] = (short)f2bf(v.y * sc);
      tile[r][c + 2] = (short)f2bf(v.z * sc);
      tile[r][c + 3] = (short)f2bf(v.w * sc);
    }
    __syncthreads();
#pragma unroll
    for (int i = 0; i < 2; i++) {
      int f = t + i * 256;
      int r = f >> 3, c8 = f & 7;
      s16x8 o;
#pragma unroll
      for (int j = 0; j < 8; j++) o[j] = tile[c8 * 8 + j][r];
      *(s16x8*)(WT + (size_t)(n0 + r) * 1024 + k0 + ((c8 ^ (r & 7)) & 7) * 8) = o;
    }
  }
}

// ---------------------------------------------------------------------------
// GEMM: A (bf16, pre-swizzled) @ BT (bf16, pre-swizzled) + bias.
// 128x128 tile, BK=64, 4 waves; global_load_lds width-16 staging.
// __launch_bounds__(256,3): cap unified VGPR so 3 blocks/CU stay resident.
// MODE 0: QKV fused (N=3072) -> qb | kb(swz) | vbT(transposed). bq pre-scaled.
// MODE 1: refKV fused (N=2048) -> kb(swz) | vbT at s>=2048.
// MODE 2: proj (N=1024) -> fp32 out.
// ---------------------------------------------------------------------------
template<int MODE>
__global__ __launch_bounds__(256, 3)
void gemm_bt(const unsigned short* __restrict__ A, const unsigned short* __restrict__ BT,
             const float* __restrict__ b0, const float* __restrict__ b1,
             const float* __restrict__ b2,
             void* __restrict__ o0, void* __restrict__ o1, void* __restrict__ o2)
{
  const int K = 1024;
  __shared__ __align__(16) short As[128][64];
  __shared__ __align__(16) short Bs[128][64];
  const int t = threadIdx.x;
  const int lane = t & 63, wid = t >> 6;
  const int wm = wid >> 1, wn = wid & 1;
  const int lr = lane & 15, lg = lane >> 4;
  const size_t m0 = (size_t)blockIdx.y * 128;
  const int n0 = blockIdx.x * 128;

  f32x4 acc[4][4];
#pragma unroll
  for (int i = 0; i < 4; i++)
#pragma unroll
    for (int j = 0; j < 4; j++) acc[i][j] = (f32x4){0.f, 0.f, 0.f, 0.f};

  const unsigned short* Abase = A + m0 * K;
  const unsigned short* Bbase = BT + (size_t)n0 * K;
  const int r_ld = t >> 3, cb_ld = t & 7;

  for (int k0 = 0; k0 < K; k0 += 64) {
#pragma unroll
    for (int i = 0; i < 4; i++) {
      int r = r_ld + i * 32;
      gload16(Abase + (size_t)r * K + k0 + cb_ld * 8,
              (short*)As + (i * 256 + wid * 64) * 8);
      gload16(Bbase + (size_t)r * K + k0 + cb_ld * 8,
              (short*)Bs + (i * 256 + wid * 64) * 8);
    }
    __syncthreads();
#pragma unroll
    for (int ks = 0; ks < 2; ks++) {
      s16x8 af[4], bfr[4];
#pragma unroll
      for (int i = 0; i < 4; i++)
        af[i] = *(const s16x8*)&As[wm * 64 + i * 16 + lr][(((ks * 4 + lg) ^ lr) & 7) * 8];
#pragma unroll
      for (int i = 0; i < 4; i++)
        bfr[i] = *(const s16x8*)&Bs[wn * 64 + i * 16 + lr][(((ks * 4 + lg) ^ lr) & 7) * 8];
#pragma unroll
      for (int mi = 0; mi < 4; mi++)
#pragma unroll
        for (int ni = 0; ni < 4; ni++)
          acc[mi][ni] = __builtin_amdgcn_mfma_f32_16x16x32_bf16(
              asbf(af[mi]), asbf(bfr[ni]), acc[mi][ni], 0, 0, 0);
    }
    __syncthreads();
  }

  const int seg = n0 >> 10;
  const float* bb = (seg == 0) ? b0 : (seg == 1 ? b1 : b2);
#pragma unroll
  for (int mi = 0; mi < 4; mi++) {
#pragma unroll
    for (int ni = 0; ni < 4; ni++) {
      int cg = n0 + wn * 64 + ni * 16 + lr;
      int c = cg & 1023;
      float bv = bb[c];
      if (MODE == 0 && seg == 0) bv *= QSCALE;
      const bool vseg = (MODE == 0 && seg == 2) || (MODE == 1 && seg == 1);
      if (MODE != 2 && vseg) {
        // transposed V: vbT[(b*16+h)*64 + d][2560], pre-swizzled per 64-s tile
        int rm0 = (int)m0 + wm * 64 + mi * 16 + lg * 4;
        int d = c & 63, hh = c >> 6;
        int bb_, s;
        if (MODE == 0) { bb_ = rm0 >> 11; s = rm0 & 2047; }
        else           { bb_ = rm0 >> 9;  s = 2048 + (rm0 & 511); }
        int scol = (s & ~63) + ((((s >> 3) ^ d) & 7) << 3) + (s & 7);
        unsigned short* dst = (unsigned short*)(MODE == 0 ? o2 : o1);
        short4 pk4;
        pk4.x = (short)f2bf(acc[mi][ni][0] + bv);
        pk4.y = (short)f2bf(acc[mi][ni][1] + bv);
        pk4.z = (short)f2bf(acc[mi][ni][2] + bv);
        pk4.w = (short)f2bf(acc[mi][ni][3] + bv);
        *(short4*)(dst + ((size_t)(bb_ * 16 + hh) * 64 + d) * 2560 + scol) = pk4;
      } else {
#pragma unroll
        for (int r = 0; r < 4; r++) {
          int rm = (int)m0 + wm * 64 + mi * 16 + lg * 4 + r;
          float val = acc[mi][ni][r] + bv;
          if (MODE == 2) {
            ((float*)o0)[(size_t)rm * 1024 + cg] = val;
          } else {
            size_t orow; unsigned short* dst; bool swz;
            if (MODE == 0) {
              if (seg == 0) { dst = (unsigned short*)o0; orow = rm; swz = false; }
              else { orow = (size_t)(rm >> 11) * 2560 + (rm & 2047);
                     dst = (unsigned short*)o1; swz = true; }
            } else {
              orow = (size_t)(rm >> 9) * 2560 + 2048 + (rm & 511);
              dst = (unsigned short*)o0; swz = true;
            }
            int cc = c;
            if (swz) cc = (c & ~63) | ((((c >> 3) ^ (int)orow) & 7) << 3) | (c & 7);
            dst[orow * 1024 + cc] = f2bf(val);
          }
        }
      }
    }
  }
}

// ---------------------------------------------------------------------------
// Flash attention v9: one-tile software pipeline — per iteration:
// stage(ti+1) ; SM(ti-1) ; QK(ti) ; PV(ti-1) ; barrier.
// sa carried across the barrier (no extra register set: SM consumes sa
// before QK overwrites it). V triple-buffered (PV reads ti-1 while
// staging ti+1). Diagonal-paired q-tiles, shared K/V fragments.
// ---------------------------------------------------------------------------
__global__ __launch_bounds__(256, 4)
void attn(const unsigned short* __restrict__ Q, const unsigned short* __restrict__ Kb,
          const unsigned short* __restrict__ VbT, unsigned short* __restrict__ Y)
{
  const int T = 2048, S = 2560, C = 1024, TREF = 512;
  __shared__ __align__(16) short Ks[2][64][64];
  __shared__ __align__(16) short Vt[3][64][64];   // Vt[vb][d][s], triple buffer
  const int t = threadIdx.x;
  const int lane = t & 63, wid = t >> 6;
  const int lr = lane & 15, lg = lane >> 4;

  // XCD-aware remap: all 16 blocks of a (b,h) on one XCD.
  const int bid = blockIdx.x;
  const int xcd = bid & 7, idx = bid >> 3;
  const int bh = xcd * 8 + (idx >> 4);
  const int bx = idx & 15;
  const int b = bh >> 4;
  const int hc = (bh & 15) * 64;
  const int qt[2] = {bx, 31 - bx};   // paired q-tiles (64 rows each)

  // Q fragments (already scaled by QSCALE via Wq/bq)
  s16x8 qf[2][2];
#pragma unroll
  for (int j = 0; j < 2; j++) {
    size_t qrow = (size_t)(b * T + qt[j] * 64 + wid * 16 + lr);
#pragma unroll
    for (int ks = 0; ks < 2; ks++)
      qf[j][ks] = *(const s16x8*)(Q + qrow * C + hc + ks * 32 + lg * 8);
  }

  float mrow[2] = {-1e30f, -1e30f}, lsum[2] = {0.f, 0.f};
  f32x4 o[2][4];
#pragma unroll
  for (int j = 0; j < 2; j++)
#pragma unroll
    for (int d = 0; d < 4; d++) o[j][d] = (f32x4){0.f, 0.f, 0.f, 0.f};

  const int nself = 32 - bx;           // self tiles 0 .. 31-bx
  const int ntiles = nself + TREF / 64;

  auto s0_of = [&](int ti2) {
    return (ti2 < nself) ? ti2 * 64 : T + (ti2 - nself) * 64;
  };
  auto act0 = [&](int ti2) { return (ti2 <= bx) || (ti2 >= nself); };
  const int r_ld = t >> 3, cb_ld = t & 7;
  auto load_K = [&](int ti2, int buf) {
    int s0 = s0_of(ti2);
    const unsigned short* Krow = Kb + (size_t)(b * S + s0) * C + hc;
#pragma unroll
    for (int i = 0; i < 2; i++)
      gload16(Krow + (size_t)(r_ld + i * 32) * C + cb_ld * 8,
              (short*)&Ks[buf][0][0] + (i * 256 + wid * 64) * 8);
  };
  auto load_V = [&](int ti2, int vb) {
    int s0 = s0_of(ti2);
    const unsigned short* Vr = VbT + (size_t)bh * 64 * S + s0;
#pragma unroll
    for (int i = 0; i < 2; i++)
      gload16(Vr + (size_t)(r_ld + i * 32) * S + cb_ld * 8,
              (short*)&Vt[vb][0][0] + (i * 256 + wid * 64) * 8);
  };

  f32x4 sa[2][4];        // QK results for the tile whose SM/PV is pending
  s16x8 pa[2][2];

  auto do_qk = [&](int tq) {
    const bool a0 = act0(tq);
#pragma unroll
    for (int j = 0; j < 2; j++)
#pragma unroll
      for (int nt = 0; nt < 4; nt++) sa[j][nt] = (f32x4){0.f, 0.f, 0.f, 0.f};
    const int kbuf = tq & 1;
    __builtin_amdgcn_s_setprio(1);
#pragma unroll
    for (int ks = 0; ks < 2; ks++) {
      s16x8 kf[4];
#pragma unroll
      for (int nt = 0; nt < 4; nt++)
        kf[nt] = *(const s16x8*)&Ks[kbuf][nt * 16 + lr][(((ks * 4 + lg) ^ lr) & 7) * 8];
#pragma unroll
      for (int nt = 0; nt < 4; nt++) {
        if (a0)
          sa[0][nt] = __builtin_amdgcn_mfma_f32_16x16x32_bf16(
              asbf(kf[nt]), asbf(qf[0][ks]), sa[0][nt], 0, 0, 0);
        sa[1][nt] = __builtin_amdgcn_mfma_f32_16x16x32_bf16(
            asbf(kf[nt]), asbf(qf[1][ks]), sa[1][nt], 0, 0, 0);
      }
    }
    __builtin_amdgcn_s_setprio(0);
  };

  auto do_sm = [&](int tp) {
    const bool a0 = act0(tp);
#pragma unroll
    for (int j = 0; j < 2; j++) {
      if (j == 0 && !a0) continue;

      if (tp == (j == 0 ? bx : nself - 1)) {   // diagonal tile for subtile j
        int qg = wid * 16 + lr;
#pragma unroll
        for (int nt = 0; nt < 4; nt++)
#pragma unroll
          for (int r = 0; r < 4; r++)
            if (nt * 16 + lg * 4 + r > qg) sa[j][nt][r] = -1e30f;
      }

      // balanced max tree
      float mm[4];
#pragma unroll
      for (int nt = 0; nt < 4; nt++)
        mm[nt] = fmaxf(fmaxf(sa[j][nt][0], sa[j][nt][1]),
                       fmaxf(sa[j][nt][2], sa[j][nt][3]));
      float lm = fmaxf(fmaxf(mm[0], mm[1]), fmaxf(mm[2], mm[3]));

      if (!__all(lm <= mrow[j] + 8.f)) {
        float tm = lm;
        tm = fmaxf(tm, __shfl_xor(tm, 16, 64));
        tm = fmaxf(tm, __shfl_xor(tm, 32, 64));
        float mn = fmaxf(mrow[j], tm);
        float alpha = __builtin_amdgcn_exp2f(mrow[j] - mn);
        mrow[j] = mn;
        lsum[j] *= alpha;
#pragma unroll
        for (int r = 0; r < 4; r++) {
          float ar = __shfl(alpha, lg * 4 + r, 64);
#pragma unroll
          for (int dt = 0; dt < 4; dt++) o[j][dt][r] *= ar;
        }
      }

      unsigned pk2[4][2];
      float rsn[4];
#pragma unroll
      for (int nt = 0; nt < 4; nt++) {
        float p0 = __builtin_amdgcn_exp2f(sa[j][nt][0] - mrow[j]);
        float p1 = __builtin_amdgcn_exp2f(sa[j][nt][1] - mrow[j]);
        float p2 = __builtin_amdgcn_exp2f(sa[j][nt][2] - mrow[j]);
        float p3 = __builtin_amdgcn_exp2f(sa[j][nt][3] - mrow[j]);
        rsn[nt] = (p0 + p1) + (p2 + p3);
        pk2[nt][0] = cvtpk(p0, p1);
        pk2[nt][1] = cvtpk(p2, p3);
      }
      lsum[j] += (rsn[0] + rsn[1]) + (rsn[2] + rsn[3]);

      // in-register exchange: build PA fragments (row=q=lr, k=s)
#pragma unroll
      for (int ks = 0; ks < 2; ks++) {
        union { unsigned w[4]; s16x8 v; } U;
#pragma unroll
        for (int w = 0; w < 4; w++) {
          int srcL = lr + (((lg & 1) * 2 + (w >> 1)) << 4);
          unsigned v0 = __shfl((int)pk2[2 * ks][w & 1], srcL, 64);
          unsigned v1 = __shfl((int)pk2[2 * ks + 1][w & 1], srcL, 64);
          U.w[w] = (lg & 2) ? v1 : v0;
        }
        pa[j][ks] = U.v;
      }
    }
  };

  auto do_pv = [&](int tp, int vb) {
    const bool a0 = act0(tp);
    __builtin_amdgcn_s_setprio(1);
#pragma unroll
    for (int ks = 0; ks < 2; ks++) {
      s16x8 vf[4];
#pragma unroll
      for (int dt = 0; dt < 4; dt++)
        vf[dt] = *(const s16x8*)&Vt[vb][dt * 16 + lr][(((ks * 4 + lg) ^ lr) & 7) * 8];
#pragma unroll
      for (int dt = 0; dt < 4; dt++) {
        if (a0)
          o[0][dt] = __builtin_amdgcn_mfma_f32_16x16x32_bf16(
              asbf(pa[0][ks]), asbf(vf[dt]), o[0][dt], 0, 0, 0);
        o[1][dt] = __builtin_amdgcn_mfma_f32_16x16x32_bf16(
            asbf(pa[1][ks]), asbf(vf[dt]), o[1][dt], 0, 0, 0);
      }
    }
    __builtin_amdgcn_s_setprio(0);
  };

  // ---- prologue ----
  load_K(0, 0);
  load_V(0, 0);
  __syncthreads();          // K0, V0 ready
  do_qk(0);                 // issue QK(0) from Ks[0]
  load_K(1, 1);             // ntiles >= 25 always
  load_V(1, 1);
  __syncthreads();          // K1, V1 ready; QK(0) ds_reads retired

  // ---- pipelined main loop ----
  for (int ti = 1; ti < ntiles; ti++) {
    if (ti + 1 < ntiles) {             // stage ti+1 first (hide HBM latency)
      load_K(ti + 1, (ti + 1) & 1);
      load_V(ti + 1, (ti + 1) % 3);
    }
    do_sm(ti - 1);                     // softmax of previous tile (sa ready)
    do_qk(ti);                         // overwrite sa with QK(ti)
    do_pv(ti - 1, (ti - 1) % 3);       // PV of previous tile
    __syncthreads();
  }
  // ---- tail: finish last tile ----
  do_sm(ntiles - 1);
  do_pv(ntiles - 1, (ntiles - 1) % 3);

  // epilogue: reduce lsum over the 4 lanes sharing each q, divide, write Y
#pragma unroll
  for (int j = 0; j < 2; j++) {
    float tot = lsum[j];
    tot += __shfl_xor(tot, 16, 64);
    tot += __shfl_xor(tot, 32, 64);
#pragma unroll
    for (int r = 0; r < 4; r++) {
      float inv = 1.0f / __shfl(tot, lg * 4 + r, 64);
      int qrow = b * T + qt[j] * 64 + wid * 16 + lg * 4 + r;
#pragma unroll
      for (int dt = 0; dt < 4; dt++) {
        int col = hc + dt * 16 + lr;
        int cb = col >> 3;
        int cs = (cb & ~7) | ((cb ^ qrow) & 7);
        Y[(size_t)qrow * C + cs * 8 + (col & 7)] = f2bf(o[j][dt][r] * inv);
      }
    }
  }
}

// ---------------------------------------------------------------------------
extern "C" void kernel_launch(void* const* d_in, const int* in_sizes, int n_in,
                              void* d_out, int out_size, void* d_ws, size_t ws_size,
                              hipStream_t stream) {
  const float* x   = (const float*)d_in[0];
  const float* ref = (const float*)d_in[1];
  const float* Wq  = (const float*)d_in[2];
  const float* bq  = (const float*)d_in[3];
  const float* Wk  = (const float*)d_in[4];
  const float* bk  = (const float*)d_in[5];
  const float* Wv  = (const float*)d_in[6];
  const float* bv  = (const float*)d_in[7];
  const float* Wrk = (const float*)d_in[8];
  const float* brk = (const float*)d_in[9];
  const float* Wrv = (const float*)d_in[10];
  const float* brv = (const float*)d_in[11];
  const float* Wp  = (const float*)d_in[12];
  const float* bp  = (const float*)d_in[13];
  float* out = (float*)d_out;

  char* ws = (char*)d_ws;
  auto alloc = [&](size_t bytes) {
    char* p = ws; ws += (bytes + 255) & ~(size_t)255; return p;
  };
  const size_t WB = (size_t)1024 * 1024 * 2;
  unsigned short* Wall = (unsigned short*)alloc(5 * WB);   // Wq|Wk|Wv|Wrk|Wrv
  unsigned short* WpT  = (unsigned short*)alloc(WB);
  unsigned short* xg  = (unsigned short*)alloc((size_t)10240 * 1024 * 2);  // x|ref
  unsigned short* rg  = xg + (size_t)8192 * 1024;
  unsigned short* qb  = (unsigned short*)alloc((size_t)8192 * 1024 * 2);
  unsigned short* kb  = (unsigned short*)alloc((size_t)4 * 2560 * 1024 * 2);
  unsigned short* vbT = (unsigned short*)alloc((size_t)4096 * 2560 * 2);
  unsigned short* yb  = (unsigned short*)alloc((size_t)8192 * 1024 * 2);

  dim3 tb(256);

  PrepArgs pa;
  pa.x = x; pa.ref = ref; pa.xg = xg;
  pa.w[0] = Wq;  pa.o[0] = Wall;
  pa.w[1] = Wk;  pa.o[1] = Wall + (size_t)1024 * 1024;
  pa.w[2] = Wv;  pa.o[2] = Wall + (size_t)2048 * 1024;
  pa.w[3] = Wrk; pa.o[3] = Wall + (size_t)3072 * 1024;
  pa.w[4] = Wrv; pa.o[4] = Wall + (size_t)4096 * 1024;
  pa.w[5] = Wp;  pa.o[5] = WpT;
  prep<<<dim3(6656), tb, 0, stream>>>(pa);

  gemm_bt<0><<<dim3(24, 64), tb, 0, stream>>>(xg, Wall, bq, bk, bv, qb, kb, vbT);
  gemm_bt<1><<<dim3(16, 16), tb, 0, stream>>>(rg, Wall + (size_t)3072 * 1024,
                                              brk, brv, nullptr, kb, vbT, nullptr);

  attn<<<dim3(1024), tb, 0, stream>>>(qb, kb, vbT, yb);

  gemm_bt<2><<<dim3(8, 64), tb, 0, stream>>>(yb, WpT, bp, bp, bp, out, out, out);
}

// Round 11
// 224.605 us; speedup vs baseline: 1.8813x; 1.8813x over previous
//
#include <hip/hip_runtime.h>
#include <hip/hip_bf16.h>

typedef short s16x4 __attribute__((ext_vector_type(4)));
typedef short s16x8 __attribute__((ext_vector_type(8)));
typedef __bf16 bf16x8 __attribute__((ext_vector_type(8)));
typedef float f32x4 __attribute__((ext_vector_type(4)));

#define DEVI static __device__ __forceinline__
#define QSCALE 0.18033688011112042f   // 0.125 * log2(e)

DEVI unsigned short f2bf(float x) {
  union { float f; unsigned u; } a; a.f = x;
  unsigned r = a.u + 0x7fffu + ((a.u >> 16) & 1u);
  return (unsigned short)(r >> 16);
}
DEVI bf16x8 asbf(s16x8 v) {
  union { s16x8 s; bf16x8 b; } u; u.s = v; return u.b;
}
DEVI unsigned cvtpk(float lo, float hi) {
  unsigned r;
  asm("v_cvt_pk_bf16_f32 %0, %1, %2" : "=v"(r) : "v"(lo), "v"(hi));
  return r;
}
DEVI void gload16(const void* g, void* l) {
  __builtin_amdgcn_global_load_lds(
      (const __attribute__((address_space(1))) void*)g,
      (__attribute__((address_space(3))) void*)l, 16, 0, 0);
}

// ---------------------------------------------------------------------------
// prep: one launch doing (a) fp32->bf16 convert of x|ref, pre-swizzled
// (blocks 0..5119) and (b) 6x weight transpose+convert, pre-swizzled
// (blocks 5120..6655). Wq (z==0) is pre-scaled by QSCALE.
// ---------------------------------------------------------------------------
struct PrepArgs {
  const float* x; const float* ref; unsigned short* xg;
  const float* w[6]; unsigned short* o[6];
};

__global__ __launch_bounds__(256)
void prep(PrepArgs a) {
  __shared__ short tile[64][65];
  const int bid = blockIdx.x, t = threadIdx.x;
  if (bid < 5120) {
    int f = bid * 256 + t;
    int row = f >> 7, c8 = f & 127;
    const float* src = (row < 8192 ? a.x + (size_t)row * 1024
                                   : a.ref + (size_t)(row - 8192) * 1024) + c8 * 8;
    float4 v0 = *(const float4*)src;
    float4 v1 = *(const float4*)(src + 4);
    s16x8 o;
    o[0] = (short)f2bf(v0.x); o[1] = (short)f2bf(v0.y);
    o[2] = (short)f2bf(v0.z); o[3] = (short)f2bf(v0.w);
    o[4] = (short)f2bf(v1.x); o[5] = (short)f2bf(v1.y);
    o[6] = (short)f2bf(v1.z); o[7] = (short)f2bf(v1.w);
    int cs = (c8 & ~7) | ((c8 ^ row) & 7);
    *(s16x8*)(a.xg + (size_t)row * 1024 + cs * 8) = o;
  } else {
    int q = bid - 5120;
    int z = q >> 8, b2 = q & 255;
    const float* __restrict__ W = a.w[z];
    unsigned short* __restrict__ WT = a.o[z];
    const float sc = (z == 0) ? QSCALE : 1.0f;
    const int n0 = (b2 & 15) * 64;
    const int k0 = (b2 >> 4) * 64;
#pragma unroll
    for (int i = 0; i < 4; i++) {
      int f = t + i * 256;
      int r = f >> 4, c = (f & 15) * 4;
      float4 v = *(const float4*)(W + (size_t)(k0 + r) * 1024 + n0 + c);
      tile[r][c + 0] = (short)f2bf(v.x * sc);
      tile[r][c + 1] = (short)f2bf(v.y * sc);
      tile[r][c + 2] = (short)f2bf(v.z * sc);
      tile[r][c + 3] = (short)f2bf(v.w * sc);
    }
    __syncthreads();
#pragma unroll
    for (int i = 0; i < 2; i++) {
      int f = t + i * 256;
      int r = f >> 3, c8 = f & 7;
      s16x8 o;
#pragma unroll
      for (int j = 0; j < 8; j++) o[j] = tile[c8 * 8 + j][r];
      *(s16x8*)(WT + (size_t)(n0 + r) * 1024 + k0 + ((c8 ^ (r & 7)) & 7) * 8) = o;
    }
  }
}

// ---------------------------------------------------------------------------
// GEMM: A (bf16, pre-swizzled) @ BT (bf16, pre-swizzled) + bias.
// 128x128 tile, BK=64, 4 waves; global_load_lds width-16 staging.
// __launch_bounds__(256,3): cap unified VGPR so 3 blocks/CU stay resident.
// MODE 0: QKV fused (N=3072) -> qb | kb(swz) | vbT(transposed). bq pre-scaled.
// MODE 1: refKV fused (N=2048) -> kb(swz) | vbT at s>=2048.
// MODE 2: proj (N=1024) -> fp32 out.
// ---------------------------------------------------------------------------
template<int MODE>
__global__ __launch_bounds__(256, 3)
void gemm_bt(const unsigned short* __restrict__ A, const unsigned short* __restrict__ BT,
             const float* __restrict__ b0, const float* __restrict__ b1,
             const float* __restrict__ b2,
             void* __restrict__ o0, void* __restrict__ o1, void* __restrict__ o2)
{
  const int K = 1024;
  __shared__ __align__(16) short As[128][64];
  __shared__ __align__(16) short Bs[128][64];
  const int t = threadIdx.x;
  const int lane = t & 63, wid = t >> 6;
  const int wm = wid >> 1, wn = wid & 1;
  const int lr = lane & 15, lg = lane >> 4;
  const size_t m0 = (size_t)blockIdx.y * 128;
  const int n0 = blockIdx.x * 128;

  f32x4 acc[4][4];
#pragma unroll
  for (int i = 0; i < 4; i++)
#pragma unroll
    for (int j = 0; j < 4; j++) acc[i][j] = (f32x4){0.f, 0.f, 0.f, 0.f};

  const unsigned short* Abase = A + m0 * K;
  const unsigned short* Bbase = BT + (size_t)n0 * K;
  const int r_ld = t >> 3, cb_ld = t & 7;

  for (int k0 = 0; k0 < K; k0 += 64) {
#pragma unroll
    for (int i = 0; i < 4; i++) {
      int r = r_ld + i * 32;
      gload16(Abase + (size_t)r * K + k0 + cb_ld * 8,
              (short*)As + (i * 256 + wid * 64) * 8);
      gload16(Bbase + (size_t)r * K + k0 + cb_ld * 8,
              (short*)Bs + (i * 256 + wid * 64) * 8);
    }
    __syncthreads();
#pragma unroll
    for (int ks = 0; ks < 2; ks++) {
      s16x8 af[4], bfr[4];
#pragma unroll
      for (int i = 0; i < 4; i++)
        af[i] = *(const s16x8*)&As[wm * 64 + i * 16 + lr][(((ks * 4 + lg) ^ lr) & 7) * 8];
#pragma unroll
      for (int i = 0; i < 4; i++)
        bfr[i] = *(const s16x8*)&Bs[wn * 64 + i * 16 + lr][(((ks * 4 + lg) ^ lr) & 7) * 8];
#pragma unroll
      for (int mi = 0; mi < 4; mi++)
#pragma unroll
        for (int ni = 0; ni < 4; ni++)
          acc[mi][ni] = __builtin_amdgcn_mfma_f32_16x16x32_bf16(
              asbf(af[mi]), asbf(bfr[ni]), acc[mi][ni], 0, 0, 0);
    }
    __syncthreads();
  }

  const int seg = n0 >> 10;
  const float* bb = (seg == 0) ? b0 : (seg == 1 ? b1 : b2);
#pragma unroll
  for (int mi = 0; mi < 4; mi++) {
#pragma unroll
    for (int ni = 0; ni < 4; ni++) {
      int cg = n0 + wn * 64 + ni * 16 + lr;
      int c = cg & 1023;
      float bv = bb[c];
      if (MODE == 0 && seg == 0) bv *= QSCALE;
      const bool vseg = (MODE == 0 && seg == 2) || (MODE == 1 && seg == 1);
      if (MODE != 2 && vseg) {
        // transposed V: vbT[(b*16+h)*64 + d][2560], pre-swizzled per 64-s tile
        int rm0 = (int)m0 + wm * 64 + mi * 16 + lg * 4;
        int d = c & 63, hh = c >> 6;
        int bb_, s;
        if (MODE == 0) { bb_ = rm0 >> 11; s = rm0 & 2047; }
        else           { bb_ = rm0 >> 9;  s = 2048 + (rm0 & 511); }
        int scol = (s & ~63) + ((((s >> 3) ^ d) & 7) << 3) + (s & 7);
        unsigned short* dst = (unsigned short*)(MODE == 0 ? o2 : o1);
        short4 pk4;
        pk4.x = (short)f2bf(acc[mi][ni][0] + bv);
        pk4.y = (short)f2bf(acc[mi][ni][1] + bv);
        pk4.z = (short)f2bf(acc[mi][ni][2] + bv);
        pk4.w = (short)f2bf(acc[mi][ni][3] + bv);
        *(short4*)(dst + ((size_t)(bb_ * 16 + hh) * 64 + d) * 2560 + scol) = pk4;
      } else {
#pragma unroll
        for (int r = 0; r < 4; r++) {
          int rm = (int)m0 + wm * 64 + mi * 16 + lg * 4 + r;
          float val = acc[mi][ni][r] + bv;
          if (MODE == 2) {
            ((float*)o0)[(size_t)rm * 1024 + cg] = val;
          } else {
            size_t orow; unsigned short* dst; bool swz;
            if (MODE == 0) {
              if (seg == 0) { dst = (unsigned short*)o0; orow = rm; swz = false; }
              else { orow = (size_t)(rm >> 11) * 2560 + (rm & 2047);
                     dst = (unsigned short*)o1; swz = true; }
            } else {
              orow = (size_t)(rm >> 9) * 2560 + 2048 + (rm & 511);
              dst = (unsigned short*)o0; swz = true;
            }
            int cc = c;
            if (swz) cc = (c & ~63) | ((((c >> 3) ^ (int)orow) & 7) << 3) | (c & 7);
            dst[orow * 1024 + cc] = f2bf(val);
          }
        }
      }
    }
  }
}

// ---------------------------------------------------------------------------
// Flash attention v8 (known-good): diagonally-paired q-tiles (bx, 31-bx),
// shared K/V fragments, direct Q fragment load (scale folded into Wq/bq),
// balanced fmax/add trees in softmax.
// ---------------------------------------------------------------------------
__global__ __launch_bounds__(256, 4)
void attn(const unsigned short* __restrict__ Q, const unsigned short* __restrict__ Kb,
          const unsigned short* __restrict__ VbT, unsigned short* __restrict__ Y)
{
  const int T = 2048, S = 2560, C = 1024, TREF = 512;
  __shared__ __align__(16) short Ks[2][64][64];
  __shared__ __align__(16) short Vt[2][64][64];   // Vt[d][s]
  const int t = threadIdx.x;
  const int lane = t & 63, wid = t >> 6;
  const int lr = lane & 15, lg = lane >> 4;

  // XCD-aware remap: all 16 blocks of a (b,h) on one XCD.
  const int bid = blockIdx.x;
  const int xcd = bid & 7, idx = bid >> 3;
  const int bh = xcd * 8 + (idx >> 4);
  const int bx = idx & 15;
  const int b = bh >> 4;
  const int hc = (bh & 15) * 64;
  const int qt[2] = {bx, 31 - bx};   // paired q-tiles (64 rows each)

  // Q fragments (already scaled by QSCALE via Wq/bq)
  s16x8 qf[2][2];
#pragma unroll
  for (int j = 0; j < 2; j++) {
    size_t qrow = (size_t)(b * T + qt[j] * 64 + wid * 16 + lr);
#pragma unroll
    for (int ks = 0; ks < 2; ks++)
      qf[j][ks] = *(const s16x8*)(Q + qrow * C + hc + ks * 32 + lg * 8);
  }

  float mrow[2] = {-1e30f, -1e30f}, lsum[2] = {0.f, 0.f};
  f32x4 o[2][4];
#pragma unroll
  for (int j = 0; j < 2; j++)
#pragma unroll
    for (int d = 0; d < 4; d++) o[j][d] = (f32x4){0.f, 0.f, 0.f, 0.f};

  const int nself = 32 - bx;           // self tiles 0 .. 31-bx
  const int ntiles = nself + TREF / 64;

  auto s0_of = [&](int ti2) {
    return (ti2 < nself) ? ti2 * 64 : T + (ti2 - nself) * 64;
  };
  const int r_ld = t >> 3, cb_ld = t & 7;
  auto load_K = [&](int ti2, int buf) {
    int s0 = s0_of(ti2);
    const unsigned short* Krow = Kb + (size_t)(b * S + s0) * C + hc;
#pragma unroll
    for (int i = 0; i < 2; i++)
      gload16(Krow + (size_t)(r_ld + i * 32) * C + cb_ld * 8,
              (short*)&Ks[buf][0][0] + (i * 256 + wid * 64) * 8);
  };
  auto load_V = [&](int ti2, int buf) {
    int s0 = s0_of(ti2);
    const unsigned short* Vr = VbT + (size_t)bh * 64 * S + s0;
#pragma unroll
    for (int i = 0; i < 2; i++)
      gload16(Vr + (size_t)(r_ld + i * 32) * S + cb_ld * 8,
              (short*)&Vt[buf][0][0] + (i * 256 + wid * 64) * 8);
  };

  load_K(0, 0);
  load_V(0, 0);
  __syncthreads();

  for (int ti = 0; ti < ntiles; ti++) {
    const int cur = ti & 1;
    const bool more = (ti + 1 < ntiles);
    if (more) { load_K(ti + 1, cur ^ 1); load_V(ti + 1, cur ^ 1); }

    // activity: subtile0 (early q-tile) sees tiles 0..bx + refs.
    const bool a0 = (ti <= bx) || (ti >= nself);

    // ---- S^T = K Q^T, shared K fragments ----
    f32x4 sa[2][4];
#pragma unroll
    for (int j = 0; j < 2; j++)
#pragma unroll
      for (int nt = 0; nt < 4; nt++) sa[j][nt] = (f32x4){0.f, 0.f, 0.f, 0.f};
    __builtin_amdgcn_s_setprio(1);
#pragma unroll
    for (int ks = 0; ks < 2; ks++) {
      s16x8 kf[4];
#pragma unroll
      for (int nt = 0; nt < 4; nt++)
        kf[nt] = *(const s16x8*)&Ks[cur][nt * 16 + lr][(((ks * 4 + lg) ^ lr) & 7) * 8];
#pragma unroll
      for (int nt = 0; nt < 4; nt++) {
        if (a0)
          sa[0][nt] = __builtin_amdgcn_mfma_f32_16x16x32_bf16(
              asbf(kf[nt]), asbf(qf[0][ks]), sa[0][nt], 0, 0, 0);
        sa[1][nt] = __builtin_amdgcn_mfma_f32_16x16x32_bf16(
            asbf(kf[nt]), asbf(qf[1][ks]), sa[1][nt], 0, 0, 0);
      }
    }
    __builtin_amdgcn_s_setprio(0);

    // ---- per-subtile mask + softmax + P-pack ----
    s16x8 pa[2][2];
#pragma unroll
    for (int j = 0; j < 2; j++) {
      if (j == 0 && !a0) continue;

      if (ti == (j == 0 ? bx : nself - 1)) {   // diagonal tile for subtile j
        int qg = wid * 16 + lr;
#pragma unroll
        for (int nt = 0; nt < 4; nt++)
#pragma unroll
          for (int r = 0; r < 4; r++)
            if (nt * 16 + lg * 4 + r > qg) sa[j][nt][r] = -1e30f;
      }

      // balanced max tree
      float mm[4];
#pragma unroll
      for (int nt = 0; nt < 4; nt++)
        mm[nt] = fmaxf(fmaxf(sa[j][nt][0], sa[j][nt][1]),
                       fmaxf(sa[j][nt][2], sa[j][nt][3]));
      float lm = fmaxf(fmaxf(mm[0], mm[1]), fmaxf(mm[2], mm[3]));

      if (!__all(lm <= mrow[j] + 8.f)) {
        float tm = lm;
        tm = fmaxf(tm, __shfl_xor(tm, 16, 64));
        tm = fmaxf(tm, __shfl_xor(tm, 32, 64));
        float mn = fmaxf(mrow[j], tm);
        float alpha = __builtin_amdgcn_exp2f(mrow[j] - mn);
        mrow[j] = mn;
        lsum[j] *= alpha;
#pragma unroll
        for (int r = 0; r < 4; r++) {
          float ar = __shfl(alpha, lg * 4 + r, 64);
#pragma unroll
          for (int dt = 0; dt < 4; dt++) o[j][dt][r] *= ar;
        }
      }

      unsigned pk2[4][2];
      float rsn[4];
#pragma unroll
      for (int nt = 0; nt < 4; nt++) {
        float p0 = __builtin_amdgcn_exp2f(sa[j][nt][0] - mrow[j]);
        float p1 = __builtin_amdgcn_exp2f(sa[j][nt][1] - mrow[j]);
        float p2 = __builtin_amdgcn_exp2f(sa[j][nt][2] - mrow[j]);
        float p3 = __builtin_amdgcn_exp2f(sa[j][nt][3] - mrow[j]);
        rsn[nt] = (p0 + p1) + (p2 + p3);
        pk2[nt][0] = cvtpk(p0, p1);
        pk2[nt][1] = cvtpk(p2, p3);
      }
      lsum[j] += (rsn[0] + rsn[1]) + (rsn[2] + rsn[3]);

      // in-register exchange: build PA fragments (row=q=lr, k=s)
#pragma unroll
      for (int ks = 0; ks < 2; ks++) {
        union { unsigned w[4]; s16x8 v; } U;
#pragma unroll
        for (int w = 0; w < 4; w++) {
          int srcL = lr + (((lg & 1) * 2 + (w >> 1)) << 4);
          unsigned v0 = __shfl((int)pk2[2 * ks][w & 1], srcL, 64);
          unsigned v1 = __shfl((int)pk2[2 * ks + 1][w & 1], srcL, 64);
          U.w[w] = (lg & 2) ? v1 : v0;
        }
        pa[j][ks] = U.v;
      }
    }

    // ---- O += P @ V, shared V fragments ----
    __builtin_amdgcn_s_setprio(1);
#pragma unroll
    for (int ks = 0; ks < 2; ks++) {
      s16x8 vf[4];
#pragma unroll
      for (int dt = 0; dt < 4; dt++)
        vf[dt] = *(const s16x8*)&Vt[cur][dt * 16 + lr][(((ks * 4 + lg) ^ lr) & 7) * 8];
#pragma unroll
      for (int dt = 0; dt < 4; dt++) {
        if (a0)
          o[0][dt] = __builtin_amdgcn_mfma_f32_16x16x32_bf16(
              asbf(pa[0][ks]), asbf(vf[dt]), o[0][dt], 0, 0, 0);
        o[1][dt] = __builtin_amdgcn_mfma_f32_16x16x32_bf16(
            asbf(pa[1][ks]), asbf(vf[dt]), o[1][dt], 0, 0, 0);
      }
    }
    __builtin_amdgcn_s_setprio(0);

    __syncthreads();
  }

  // epilogue: reduce lsum over the 4 lanes sharing each q, divide, write Y
#pragma unroll
  for (int j = 0; j < 2; j++) {
    float tot = lsum[j];
    tot += __shfl_xor(tot, 16, 64);
    tot += __shfl_xor(tot, 32, 64);
#pragma unroll
    for (int r = 0; r < 4; r++) {
      float inv = 1.0f / __shfl(tot, lg * 4 + r, 64);
      int qrow = b * T + qt[j] * 64 + wid * 16 + lg * 4 + r;
#pragma unroll
      for (int dt = 0; dt < 4; dt++) {
        int col = hc + dt * 16 + lr;
        int cb = col >> 3;
        int cs = (cb & ~7) | ((cb ^ qrow) & 7);
        Y[(size_t)qrow * C + cs * 8 + (col & 7)] = f2bf(o[j][dt][r] * inv);
      }
    }
  }
}

// ---------------------------------------------------------------------------
extern "C" void kernel_launch(void* const* d_in, const int* in_sizes, int n_in,
                              void* d_out, int out_size, void* d_ws, size_t ws_size,
                              hipStream_t stream) {
  const float* x   = (const float*)d_in[0];
  const float* ref = (const float*)d_in[1];
  const float* Wq  = (const float*)d_in[2];
  const float* bq  = (const float*)d_in[3];
  const float* Wk  = (const float*)d_in[4];
  const float* bk  = (const float*)d_in[5];
  const float* Wv  = (const float*)d_in[6];
  const float* bv  = (const float*)d_in[7];
  const float* Wrk = (const float*)d_in[8];
  const float* brk = (const float*)d_in[9];
  const float* Wrv = (const float*)d_in[10];
  const float* brv = (const float*)d_in[11];
  const float* Wp  = (const float*)d_in[12];
  const float* bp  = (const float*)d_in[13];
  float* out = (float*)d_out;

  char* ws = (char*)d_ws;
  auto alloc = [&](size_t bytes) {
    char* p = ws; ws += (bytes + 255) & ~(size_t)255; return p;
  };
  const size_t WB = (size_t)1024 * 1024 * 2;
  unsigned short* Wall = (unsigned short*)alloc(5 * WB);   // Wq|Wk|Wv|Wrk|Wrv
  unsigned short* WpT  = (unsigned short*)alloc(WB);
  unsigned short* xg  = (unsigned short*)alloc((size_t)10240 * 1024 * 2);  // x|ref
  unsigned short* rg  = xg + (size_t)8192 * 1024;
  unsigned short* qb  = (unsigned short*)alloc((size_t)8192 * 1024 * 2);
  unsigned short* kb  = (unsigned short*)alloc((size_t)4 * 2560 * 1024 * 2);
  unsigned short* vbT = (unsigned short*)alloc((size_t)4096 * 2560 * 2);
  unsigned short* yb  = (unsigned short*)alloc((size_t)8192 * 1024 * 2);

  dim3 tb(256);

  PrepArgs pa;
  pa.x = x; pa.ref = ref; pa.xg = xg;
  pa.w[0] = Wq;  pa.o[0] = Wall;
  pa.w[1] = Wk;  pa.o[1] = Wall + (size_t)1024 * 1024;
  pa.w[2] = Wv;  pa.o[2] = Wall + (size_t)2048 * 1024;
  pa.w[3] = Wrk; pa.o[3] = Wall + (size_t)3072 * 1024;
  pa.w[4] = Wrv; pa.o[4] = Wall + (size_t)4096 * 1024;
  pa.w[5] = Wp;  pa.o[5] = WpT;
  prep<<<dim3(6656), tb, 0, stream>>>(pa);

  gemm_bt<0><<<dim3(24, 64), tb, 0, stream>>>(xg, Wall, bq, bk, bv, qb, kb, vbT);
  gemm_bt<1><<<dim3(16, 16), tb, 0, stream>>>(rg, Wall + (size_t)3072 * 1024,
                                              brk, brv, nullptr, kb, vbT, nullptr);

  attn<<<dim3(1024), tb, 0, stream>>>(qb, kb, vbT, yb);

  gemm_bt<2><<<dim3(8, 64), tb, 0, stream>>>(yb, WpT, bp, bp, bp, out, out, out);
}